// Round 12
// baseline (279.521 us; speedup 1.0000x reference)
//
#include <hip/hip_runtime.h>
#include <hip/hip_bf16.h>

// Round 20: BW-model attack — cut staged bytes AND raise occupancy together.
//   Model (reconciles all 11 rounds): GEMM time ~ staged_bytes / BW_eff where
//   BW_eff ~ occupancy-scaled per-CU L2 BW (~56 B/cy ceiling). R8/R11 wins
//   were occupancy; R4/R10 byte-cuts were cancelled by occupancy loss.
//   - 128x128 tile, BK=64, 1024 thr = 16 waves (4m x 4n, wave 32x32,
//     acc[2][2], 8 MFMA/step/wave — same barrier rate as R11 best)
//   - bytes factor 0.0234 -> 0.0156 (-33%)
//   - dbuf 2x32KB = 64KB -> 2 blocks/CU = 32 waves/CU (HW max), forced by
//     __launch_bounds__(1024, 8) (64-VGPR cap; K-loop ~50 VGPR, fits)
//   - staging exactly 2 loads/thread (1A+1B chunk), counted vmcnt(2)
//   - M padded 1664 (13 tiles, R4's proven pack + u<400 guards)
//   - grid 416 = 8 XCD x 52 bijective; per-XCD set ~3.9MB ~ L2
//   - same K-accumulation order -> absmax unchanged

#define B_SZ     4096
#define LSTM_N   400
#define MPAD     1664   // 13 * 128
#define MT       13
#define VOCAB    73
#define NATTN    10
#define CHARLEN  64
#define KP1      512
#define KP23     896

typedef _Float16 half8 __attribute__((ext_vector_type(8)));
typedef __attribute__((ext_vector_type(4))) float floatx4;

__device__ __forceinline__ void gload_lds16(const void* g, void* l) {
    __builtin_amdgcn_global_load_lds(
        (const __attribute__((address_space(1))) void*)g,
        (__attribute__((address_space(3))) void*)l, 16, 0, 0);
}

// [row][64-half] LDS tile, XOR-swizzled 16B granules within each 128B row
__device__ __forceinline__ int lds_off(int r, int g) {
    return (r << 6) + ((((g ^ r) & 7)) << 3);
}

// ---------------------------------------------------------------- pack (all)
// Layouts:
//   X1 (KP1):  [w_prev 0..73 | inputs 73..76 | h1 76..476 | 0pad]
//   XA (KP1):  [h1n 0..400 | w_prev 400..473 | inputs 473..476 | 0pad]
//   X2 (KP23): [h1n 0..400 | inputs 400..403 | w 403..476 | h2 476..876 | 0pad]
//   X3 (KP23): [h2n 0..400 | inputs 400..403 | w 403..476 | h3 476..876 | 0pad]
// W rows: n = 4u+g <- src row g*400+u; rows with u>=400 zero (M padding).
#define CW1   106496            // 1664 * 64
#define CW23  186368            // 1664 * 112
#define CWA   4096              // 64 * 64
#define CX1   262144            // 4096 * 64
#define CXA   57344             // 4096 * 14   (cols 400..512)
#define CX23  253952            // 4096 * 62   (cols 400..896, both X2 & X3)
#define O1    (CW1)
#define O2    (O1 + CW23)
#define O3    (O2 + CW23)
#define O4    (O3 + CWA)
#define O5    (O4 + CX1)
#define O6    (O5 + CXA)
#define O7    (O6 + CX23)       // 1056768 = 256 * 4128

__global__ __launch_bounds__(256) void pack_all(const float* __restrict__ Wih1,
                                                const float* __restrict__ Whh1,
                                                const float* __restrict__ Wih2,
                                                const float* __restrict__ Whh2,
                                                const float* __restrict__ Wih3,
                                                const float* __restrict__ Whh3,
                                                const float* __restrict__ W_attn,
                                                const float* __restrict__ w_prev,
                                                const float* __restrict__ inputs,
                                                const float* __restrict__ h1,
                                                const float* __restrict__ h2,
                                                const float* __restrict__ h3,
                                                _Float16* __restrict__ W1,
                                                _Float16* __restrict__ W2,
                                                _Float16* __restrict__ W3,
                                                _Float16* __restrict__ Wa,
                                                _Float16* __restrict__ X1,
                                                _Float16* __restrict__ XA,
                                                _Float16* __restrict__ X2,
                                                _Float16* __restrict__ X3)
{
    const int id = blockIdx.x * 256 + threadIdx.x;
    half8 hv;

    if (id < O1) {                       // ---- W1: 1664 x 512
        const int row = id >> 6;
        const int k0  = (id & 63) << 3;
        const int u = row >> 2, g = row & 3;
        const int src = g * 400 + u;
#pragma unroll
        for (int e = 0; e < 8; e++) {
            const int k = k0 + e;
            float x = 0.f;
            if (u < 400) {
                if (k < 76)           x = Wih1[(size_t)src * 76 + k];
                else if (k < 476)     x = Whh1[(size_t)src * 400 + (k - 76)];
            }
            hv[e] = (_Float16)x;
        }
        *(half8*)(W1 + (size_t)row * KP1 + k0) = hv;
    } else if (id < O3) {                // ---- W2 / W3: 1664 x 896
        const int id2 = id - O1;
        const bool is3 = (id2 >= CW23);
        const int id3 = is3 ? id2 - CW23 : id2;
        const int row = id3 / 112;
        const int k0  = (id3 - row * 112) << 3;
        const int u = row >> 2, g = row & 3;
        const int src = g * 400 + u;
        const float* Wih = is3 ? Wih3 : Wih2;
        const float* Whh = is3 ? Whh3 : Whh2;
#pragma unroll
        for (int e = 0; e < 8; e++) {
            const int k = k0 + e;
            float x = 0.f;
            if (u < 400) {
                if (k < 400)          x = Wih[(size_t)src * 476 + 3 + k];
                else if (k < 403)     x = Wih[(size_t)src * 476 + (k - 400)];
                else if (k < 476)     x = Wih[(size_t)src * 476 + k];
                else if (k < 876)     x = Whh[(size_t)src * 400 + (k - 476)];
            }
            hv[e] = (_Float16)x;
        }
        *(half8*)((is3 ? W3 : W2) + (size_t)row * KP23 + k0) = hv;
    } else if (id < O4) {                // ---- Wa: 64 x 512 (rows >=30 zero)
        const int id4 = id - O3;
        const int row = id4 >> 6;
        const int k0  = (id4 & 63) << 3;
#pragma unroll
        for (int e = 0; e < 8; e++) {
            const int k = k0 + e;
            float x = 0.f;
            if (row < 30) {
                if (k < 400)      x = W_attn[(size_t)row * 476 + 76 + k];
                else if (k < 473) x = W_attn[(size_t)row * 476 + (k - 400)];
                else if (k < 476) x = W_attn[(size_t)row * 476 + 73 + (k - 473)];
            }
            hv[e] = (_Float16)x;
        }
        *(half8*)(Wa + (size_t)row * KP1 + k0) = hv;
    } else if (id < O5) {                // ---- X1: 4096 x 512
        const int id5 = id - O4;
        const int b  = id5 >> 6;
        const int k0 = (id5 & 63) << 3;
#pragma unroll
        for (int e = 0; e < 8; e++) {
            const int k = k0 + e;
            float x = 0.f;
            if (k < 73)           x = w_prev[(size_t)b * 73 + k];
            else if (k < 76)      x = inputs[(size_t)b * 3 + (k - 73)];
            else if (k < 476)     x = h1[(size_t)b * 400 + (k - 76)];
            hv[e] = (_Float16)x;
        }
        *(half8*)(X1 + (size_t)b * KP1 + k0) = hv;
    } else if (id < O6) {                // ---- XA cols 400..512
        const int id6 = id - O5;
        const int b  = id6 / 14;
        const int k0 = 400 + ((id6 - b * 14) << 3);
#pragma unroll
        for (int e = 0; e < 8; e++) {
            const int k = k0 + e;
            float x = 0.f;
            if (k < 473)          x = w_prev[(size_t)b * 73 + (k - 400)];
            else if (k < 476)     x = inputs[(size_t)b * 3 + (k - 473)];
            hv[e] = (_Float16)x;
        }
        *(half8*)(XA + (size_t)b * KP1 + k0) = hv;
    } else if (id < O7) {                // ---- X2+X3 cols 400..896
        const int id7 = id - O6;
        const int b  = id7 / 62;
        const int k0 = 400 + ((id7 - b * 62) << 3);
        half8 h2v, h3v;
#pragma unroll
        for (int e = 0; e < 8; e++) {
            const int k = k0 + e;
            float x2 = 0.f, x3 = 0.f;
            if (k < 403)                    { x2 = inputs[(size_t)b * 3 + (k - 400)]; x3 = x2; }
            else if (k >= 476 && k < 876)   { x2 = h2[(size_t)b * 400 + (k - 476)];
                                              x3 = h3[(size_t)b * 400 + (k - 476)]; }
            h2v[e] = (_Float16)x2;
            h3v[e] = (_Float16)x3;
        }
        *(half8*)(X2 + (size_t)b * KP23 + k0) = h2v;
        *(half8*)(X3 + (size_t)b * KP23 + k0) = h3v;
    }
}

// ---------------------------------------------------------------- fused GEMM
// 128(rows) x 128(batch) tile, BK=64, 1024 thr = 16 waves (4m x 4n), wave
// 32x32 (acc[2][2], 8 MFMAs/K-step). Dbuf 2x32KB = 64KB; launch_bounds
// (1024,8) caps VGPR at 64 -> 2 blocks/CU = 32 waves/CU (HW max).
// Staging: wave w stages A chunk w + B chunk w (exactly 2 loads/thread).
template<int KP>
__global__ __launch_bounds__(1024, 8) void gemm_fused_t(const _Float16* __restrict__ Wm,
                                                        const _Float16* __restrict__ X,
                                                        const float* __restrict__ bias,
                                                        const float* __restrict__ c_in,
                                                        _Float16* __restrict__ d1, int ld1,
                                                        _Float16* __restrict__ d2, int ld2,
                                                        float* __restrict__ fout)
{
    __shared__ _Float16 lds[2][256 * 64];   // [A 128 rows | B 128 rows] x2 = 64KB

    const int t    = threadIdx.x;
    const int w    = t >> 6;                // 0..15
    const int lane = t & 63;
    const int quad = lane >> 4;
    const int l16  = lane & 15;
    // bijective XCD chunks: 416 = 8 x 52; each XCD: 4 batch-tiles x 13 rows
    const int fid  = blockIdx.y * 32 + blockIdx.x;
    const int xcd  = fid & 7;
    const int loc  = fid >> 3;              // 0..51
    const int bx   = xcd * 4 + loc / 13;    // batch tile 0..31
    const int by   = loc % 13;              // row tile 0..12
    const int m0   = by * 128;
    const int n0   = bx * 128;
    const int wm   = (w >> 2) * 32;         // 0,32,64,96
    const int wn   = (w & 3) * 32;          // 0,32,64,96
    const int lr   = lane >> 3;             // 0..7 row-in-8
    const int gq   = (lane & 7) ^ lr;       // XOR-swizzled granule

    floatx4 acc[2][2] = {};

    // exactly 2 loads/thread per K-step: A chunk w, B chunk w
    auto stage = [&](int sb, int k0) {
        gload_lds16(Wm + (size_t)(m0 + w * 8 + lr) * KP + k0 + gq * 8,
                    &lds[sb][(w * 8) * 64]);
        gload_lds16(X + (size_t)(n0 + w * 8 + lr) * KP + k0 + gq * 8,
                    &lds[sb][(128 + w * 8) * 64]);
    };

    stage(0, 0);
    constexpr int NT = KP / 64;
#pragma unroll
    for (int kt = 0; kt < NT; kt++) {
        const int sb = kt & 1;
        if (kt + 1 < NT) {
            stage(sb ^ 1, (kt + 1) * 64);
            asm volatile("s_waitcnt vmcnt(2)" ::: "memory");
        } else {
            asm volatile("s_waitcnt vmcnt(0)" ::: "memory");
        }
        __builtin_amdgcn_s_barrier();
        __builtin_amdgcn_sched_barrier(0);

#pragma unroll
        for (int h = 0; h < 2; h++) {
            half8 af[2], bf[2];
#pragma unroll
            for (int i = 0; i < 2; i++)
                af[i] = *(const half8*)(&lds[sb][lds_off(wm + i * 16 + l16, h * 4 + quad)]);
#pragma unroll
            for (int i = 0; i < 2; i++)
                bf[i] = *(const half8*)(&lds[sb][lds_off(128 + wn + i * 16 + l16, h * 4 + quad)]);
            __builtin_amdgcn_s_setprio(1);
#pragma unroll
            for (int mt = 0; mt < 2; mt++)
#pragma unroll
                for (int nt = 0; nt < 2; nt++)
                    acc[mt][nt] = __builtin_amdgcn_mfma_f32_16x16x32_f16(
                        af[mt], bf[nt], acc[mt][nt], 0, 0, 0);
            __builtin_amdgcn_s_setprio(0);
        }
        __builtin_amdgcn_s_barrier();
    }
    __builtin_amdgcn_sched_barrier(0);

    // ---------------- epilogue: descattered I/O via LDS transpose ----------
    // Block: 32 units x 128 batch rows; u guard for by=12 (nvalid=16).
    const int u0     = by * 32;
    const int nvalid = (u0 + 32 <= LSTM_N) ? 32 : (LSTM_N - u0);
    float*    Cs   = (float*)&lds[0][0];      // [128][36] f32 (18KB)
    _Float16* Hs16 = (_Float16*)&lds[1][0];   // [128][40] f16 (10KB)
    float*    Hs32 = (float*)&lds[1][0];      // [128][36] f32 (18KB)
    {   // stage c tile: 8 thr/row, 1 float4 each
        const int bl = t >> 3;
        const int p  = t & 7;
        if (p * 4 < nvalid) {
            floatx4 cv = *(const floatx4*)(c_in + (size_t)(n0 + bl) * LSTM_N + u0 + p * 4);
            *(floatx4*)(Cs + bl * 36 + p * 4) = cv;
        }
    }
    __syncthreads();

#pragma unroll
    for (int mt = 0; mt < 2; mt++) {
        const int ul = (wm >> 2) + mt * 4 + quad;   // 0..31 local unit
        const int u  = u0 + ul;
        const bool uv = ul < nvalid;
        const float bi  = uv ? bias[u] : 0.f;
        const float bff = uv ? bias[400 + u] : 0.f;
        const float bg  = uv ? bias[800 + u] : 0.f;
        const float bo  = uv ? bias[1200 + u] : 0.f;
#pragma unroll
        for (int nt = 0; nt < 2; nt++) {
            const int bl = wn + nt * 16 + l16;      // local batch 0..127
            float gi = acc[mt][nt][0] + bi;
            float gf = acc[mt][nt][1] + bff;
            float gg = acc[mt][nt][2] + bg;
            float go = acc[mt][nt][3] + bo;
            float si = 1.f / (1.f + expf(-gi));
            float sf = 1.f / (1.f + expf(-gf));
            float so = 1.f / (1.f + expf(-go));
            float cn = sf * (uv ? Cs[bl * 36 + ul] : 0.f) + si * tanhf(gg);
            float h  = so * tanhf(cn);
            if (uv) {
                if (fout) Hs32[bl * 36 + ul] = h;
                else      Hs16[bl * 40 + ul] = (_Float16)h;
            }
        }
    }
    __syncthreads();

    if (fout) {   // fp32: 8 float4 chunks/row x 128 rows = 1024, 1/thread
        const int bl = t >> 3;
        const int ch = t & 7;
        if (ch * 4 < nvalid)
            *(floatx4*)(fout + (size_t)(n0 + bl) * LSTM_N + u0 + ch * 4) =
                *(const floatx4*)(Hs32 + bl * 36 + ch * 4);
    } else if (t < 512) {   // fp16: 4 half8/row x 128 rows = 512 chunks
        const int bl = t >> 2;
        const int ch = t & 3;
        if (ch * 8 < nvalid) {
            half8 hvv = *(const half8*)(Hs16 + bl * 40 + ch * 8);
            *(half8*)(d1 + (size_t)(n0 + bl) * ld1 + u0 + ch * 8) = hvv;
            if (d2) *(half8*)(d2 + (size_t)(n0 + bl) * ld2 + u0 + ch * 8) = hvv;
        }
    }
}

// ---------------------------------------------------------------- attn (fused)
// wave = one batch row; 4 waves/block; grid B/4. (Unchanged.)
__global__ __launch_bounds__(256) void attn_fused(const _Float16* __restrict__ Wa,
                                                  const _Float16* __restrict__ XA,
                                                  const float* __restrict__ b_attn,
                                                  const float* __restrict__ kappa,
                                                  const float* __restrict__ AV,
                                                  const int* __restrict__ alen,
                                                  _Float16* __restrict__ X2,
                                                  _Float16* __restrict__ X3)
{
    __shared__ _Float16 Wa_s[30 * KP1];     // 30 KB
    __shared__ float prm[4][32];
    __shared__ float phi_s[4][CHARLEN];

    const int t = threadIdx.x;
#pragma unroll
    for (int i = 0; i < 8; i++) {
        const int idx = t + i * 256;
        if (idx < 1920) {
            const int row = idx >> 6;
            const int c8  = (idx & 63) << 3;
            *(half8*)(&Wa_s[row * KP1 + c8]) = *(const half8*)(Wa + (size_t)row * KP1 + c8);
        }
    }
    __syncthreads();

    const int wave = t >> 6;
    const int lane = t & 63;
    const int b = blockIdx.x * 4 + wave;

    half8 xa = *(const half8*)(XA + (size_t)b * KP1 + lane * 8);
    float xf[8];
#pragma unroll
    for (int e = 0; e < 8; e++) xf[e] = (float)xa[e];

    float myp = 0.f;
#pragma unroll
    for (int m = 0; m < 30; m++) {
        half8 wv = *(const half8*)(&Wa_s[m * KP1 + lane * 8]);
        float s = 0.f;
#pragma unroll
        for (int e = 0; e < 8; e++) s += (float)wv[e] * xf[e];
#pragma unroll
        for (int sh = 32; sh >= 1; sh >>= 1) s += __shfl_xor(s, sh, 64);
        if (lane == m) myp = s;
    }

    if (lane < 30) {
        float p  = myp + b_attn[lane];
        float sp = (p > 20.f) ? p : log1pf(expf(p));
        float v;
        if (lane < 10)      v = sp;
        else if (lane < 20) v = fmaxf(sp, 0.01f);
        else                v = kappa[(size_t)b * NATTN + (lane - 20)] + sp * (1.f / 25.f);
        prm[wave][lane] = v;
    }
    __syncthreads();

    const int len = alen[b];
    {
        int c = lane;
        float phi = 0.f;
#pragma unroll
        for (int j = 0; j < NATTN; j++) {
            float d = prm[wave][20 + j] - (float)c;
            phi += prm[wave][j] * expf(-d * d / prm[wave][10 + j]);
        }
        phi_s[wave][c] = (c < len) ? phi : 0.f;
    }
    __syncthreads();

    for (int v0 = 0; v0 < VOCAB; v0 += 64) {
        const int v = v0 + lane;
        if (v < VOCAB) {
            const float* avb = AV + (size_t)b * CHARLEN * VOCAB + v;
            float s = 0.f;
            for (int c = 0; c < len; c++)
                s += phi_s[wave][c] * avb[(size_t)c * VOCAB];
            _Float16 wv = (_Float16)s;
            X2[(size_t)b * KP23 + 403 + v] = wv;
            X3[(size_t)b * KP23 + 403 + v] = wv;
        }
    }
}

// ---------------------------------------------------------------- launch
extern "C" void kernel_launch(void* const* d_in, const int* in_sizes, int n_in,
                              void* d_out, int out_size, void* d_ws, size_t ws_size,
                              hipStream_t stream)
{
    const float* inputs = (const float*)d_in[0];
    const float* h1     = (const float*)d_in[1];
    const float* c1     = (const float*)d_in[2];
    const float* h2     = (const float*)d_in[3];
    const float* c2     = (const float*)d_in[4];
    const float* h3     = (const float*)d_in[5];
    const float* c3     = (const float*)d_in[6];
    const float* kappa  = (const float*)d_in[7];
    const float* w_prev = (const float*)d_in[8];
    const float* AV     = (const float*)d_in[9];
    const int*   alen   = (const int*)d_in[10];
    const float* W_ih1  = (const float*)d_in[11];
    const float* W_hh1  = (const float*)d_in[12];
    const float* b1     = (const float*)d_in[13];
    const float* W_attn = (const float*)d_in[14];
    const float* b_attn = (const float*)d_in[15];
    const float* W_ih2  = (const float*)d_in[16];
    const float* W_hh2  = (const float*)d_in[17];
    const float* b2     = (const float*)d_in[18];
    const float* W_ih3  = (const float*)d_in[19];
    const float* W_hh3  = (const float*)d_in[20];
    const float* b3     = (const float*)d_in[21];
    float* out = (float*)d_out;

    char* p = (char*)d_ws;
    _Float16* X1 = (_Float16*)p; p += (size_t)B_SZ * KP1 * 2;
    _Float16* XA = (_Float16*)p; p += (size_t)B_SZ * KP1 * 2;
    _Float16* X2 = (_Float16*)p; p += (size_t)B_SZ * KP23 * 2;
    _Float16* X3 = (_Float16*)p; p += (size_t)B_SZ * KP23 * 2;
    _Float16* W1 = (_Float16*)p; p += (size_t)MPAD * KP1 * 2;
    _Float16* W2 = (_Float16*)p; p += (size_t)MPAD * KP23 * 2;
    _Float16* W3 = (_Float16*)p; p += (size_t)MPAD * KP23 * 2;
    _Float16* Wa = (_Float16*)p; p += (size_t)64 * KP1 * 2;

    pack_all<<<O7 / 256, 256, 0, stream>>>(W_ih1, W_hh1, W_ih2, W_hh2,
                                           W_ih3, W_hh3, W_attn,
                                           w_prev, inputs, h1, h2, h3,
                                           W1, W2, W3, Wa, X1, XA, X2, X3);

    const dim3 fgrid(32, MT);   // 416 blocks = 8 XCD x 52

    // LSTM1: h1n -> XA col 0 (attn input) + X2 col 0
    gemm_fused_t<KP1><<<fgrid, 1024, 0, stream>>>(W1, X1, b1, c1,
                                                  XA, KP1, X2, KP23, nullptr);
    // attention: params (wave-dot GEMM) + phi + einsum -> w into X2, X3
    attn_fused<<<B_SZ / 4, 256, 0, stream>>>(Wa, XA, b_attn, kappa, AV, alen, X2, X3);
    // LSTM2: h2n -> X3 col 0
    gemm_fused_t<KP23><<<fgrid, 1024, 0, stream>>>(W2, X2, b2, c2,
                                                   X3, KP23, nullptr, 0, nullptr);
    // LSTM3: h3n -> out (fp32)
    gemm_fused_t<KP23><<<fgrid, 1024, 0, stream>>>(W3, X3, b3, c3,
                                                   nullptr, 0, nullptr, 0, out);
}